// Round 1
// 210.842 us; speedup vs baseline: 1.0086x; 1.0086x over previous
//
#include <hip/hip_runtime.h>
#include <math.h>

// Problem constants (from reference): B=32, I=2048, O=32, C=16, U=32
#define B_   32
#define I_   2048
#define O_   32
#define C_   16
#define U_   32
#define NCOL (O_ * U_)        // 1024 output columns (o,u)

// R4 tiling: TI=8 i-values per block, 2-way o-split -> 512 blocks (unchanged
// grid/occupancy: 2 blocks/CU, 4 waves/SIMD) but partial slice shrinks
// 128KB -> 64KB. ws round-trip halves: 128MB -> 64MB total HBM.
#define TI   8                // i-values per block
#define OSPL 2                // o-split factor
#define OH_  (O_ / OSPL)      // 16 o-values per block
#define NIH  (I_ / TI)        // 256 i-chunks
#define NBLK (NIH * OSPL)     // 512 blocks
#define SLICE (B_ * OH_ * U_) // 16384 floats per partial slice (64 KB)
#define XS   36               // x LDS stride: mult-of-4 (b128 align), pad vs bank conflicts

// softmax over the singleton axis of b_log is identically 1 -> routing
// iterations are no-ops. Output = squash(sum_{i,c} x[b,i,c] * w[i,o,c,u]).

__global__ __launch_bounds__(512, 4) void caps_partial(const float* __restrict__ x,
                                                       const float* __restrict__ w,
                                                       float* __restrict__ ws) {
    __shared__ float xs[TI * C_ * XS];   // xs[rem*36 + b], rem = il*C + c (128 rems)
    const int tid = threadIdx.x;         // 0..511
    const int ih  = blockIdx.x & (NIH - 1);   // i-chunk
    const int oh  = blockIdx.x >> 8;          // o-half
    const int i0  = ih * TI;
    const int o0  = oh * OH_;

    // Stage x[:, i0:i0+TI, :] -> xs[rem*XS + b]. Global read coalesced (rem
    // fast). Write has 8-way bank aliasing but is only 8 instrs/thread, once.
    for (int k = tid; k < B_ * TI * C_; k += 512) {
        int b   = k >> 7;        // / (TI*C_) == 128
        int rem = k & 127;
        xs[rem * XS + b] = x[(size_t)b * (I_ * C_) + (size_t)i0 * C_ + rem];
    }
    __syncthreads();

    // thread decode: bh = batch-octet (8 b each), oo = o within half, u4 = u quad
    const int bh = tid >> 7;             // 0..3
    const int ct = tid & 127;
    const int oo = ct >> 3;              // 0..15
    const int u4 = (ct & 7) << 2;
    const float* wp = w + (size_t)i0 * (O_ * C_ * U_) + (size_t)(o0 + oo) * (C_ * U_) + u4;

    float4 acc[8];                       // acc[bl] : b = bh*8+bl, u = u4..u4+3
#pragma unroll
    for (int b = 0; b < 8; ++b) acc[b] = make_float4(0.f, 0.f, 0.f, 0.f);

    for (int il = 0; il < TI; ++il) {
        const float* wpi = wp + (size_t)il * (O_ * C_ * U_);
        const float* xr  = &xs[(il * C_) * XS + bh * 8];
#pragma unroll
        for (int cc = 0; cc < C_; cc += 4) {
            float4 wv[4];
#pragma unroll
            for (int j = 0; j < 4; ++j)
                wv[j] = *(const float4*)(wpi + (cc + j) * U_);   // 16B/lane, 128B segments
#pragma unroll
            for (int j = 0; j < 4; ++j) {
                const float* xc = xr + (cc + j) * XS;
                float4 xa = *(const float4*)(xc);        // b = bh*8 + 0..3 (broadcast)
                float4 xb = *(const float4*)(xc + 4);    // b = bh*8 + 4..7 (broadcast)
                acc[0].x = fmaf(xa.x, wv[j].x, acc[0].x);
                acc[0].y = fmaf(xa.x, wv[j].y, acc[0].y);
                acc[0].z = fmaf(xa.x, wv[j].z, acc[0].z);
                acc[0].w = fmaf(xa.x, wv[j].w, acc[0].w);
                acc[1].x = fmaf(xa.y, wv[j].x, acc[1].x);
                acc[1].y = fmaf(xa.y, wv[j].y, acc[1].y);
                acc[1].z = fmaf(xa.y, wv[j].z, acc[1].z);
                acc[1].w = fmaf(xa.y, wv[j].w, acc[1].w);
                acc[2].x = fmaf(xa.z, wv[j].x, acc[2].x);
                acc[2].y = fmaf(xa.z, wv[j].y, acc[2].y);
                acc[2].z = fmaf(xa.z, wv[j].z, acc[2].z);
                acc[2].w = fmaf(xa.z, wv[j].w, acc[2].w);
                acc[3].x = fmaf(xa.w, wv[j].x, acc[3].x);
                acc[3].y = fmaf(xa.w, wv[j].y, acc[3].y);
                acc[3].z = fmaf(xa.w, wv[j].z, acc[3].z);
                acc[3].w = fmaf(xa.w, wv[j].w, acc[3].w);
                acc[4].x = fmaf(xb.x, wv[j].x, acc[4].x);
                acc[4].y = fmaf(xb.x, wv[j].y, acc[4].y);
                acc[4].z = fmaf(xb.x, wv[j].z, acc[4].z);
                acc[4].w = fmaf(xb.x, wv[j].w, acc[4].w);
                acc[5].x = fmaf(xb.y, wv[j].x, acc[5].x);
                acc[5].y = fmaf(xb.y, wv[j].y, acc[5].y);
                acc[5].z = fmaf(xb.y, wv[j].z, acc[5].z);
                acc[5].w = fmaf(xb.y, wv[j].w, acc[5].w);
                acc[6].x = fmaf(xb.z, wv[j].x, acc[6].x);
                acc[6].y = fmaf(xb.z, wv[j].y, acc[6].y);
                acc[6].z = fmaf(xb.z, wv[j].z, acc[6].z);
                acc[6].w = fmaf(xb.z, wv[j].w, acc[6].w);
                acc[7].x = fmaf(xb.w, wv[j].x, acc[7].x);
                acc[7].y = fmaf(xb.w, wv[j].y, acc[7].y);
                acc[7].z = fmaf(xb.w, wv[j].z, acc[7].z);
                acc[7].w = fmaf(xb.w, wv[j].w, acc[7].w);
            }
        }
    }

    // ws[blk][b][oo][u], slice = blockIdx (oh*256+ih). Coalesced float4 stores.
    float* op = ws + (size_t)blockIdx.x * SLICE + (size_t)(bh * 8) * (OH_ * U_)
                + oo * U_ + u4;
#pragma unroll
    for (int bl = 0; bl < 8; ++bl)
        *(float4*)(op + (size_t)bl * (OH_ * U_)) = acc[bl];
}

// Sum 256 i-chunk partials per element (2 threads/element over halves),
// then squash over u (32 consecutive e = one (b,o) group; shuffle reduce).
__global__ __launch_bounds__(256) void caps_reduce_squash(const float* __restrict__ ws,
                                                          float* __restrict__ out) {
    __shared__ float sh[128];
    const int tl = threadIdx.x & 127;
    const int ph = threadIdx.x >> 7;           // i-chunk half
    const int e  = blockIdx.x * 128 + tl;      // e in [0, 32768)
    const int b  = e >> 10;
    const int o  = (e >> 5) & 31;
    const int u  = e & 31;
    const int oh = o >> 4;
    const int oo = o & 15;
    const float* p = ws + (size_t)oh * NIH * SLICE + (size_t)ph * (NIH / 2) * SLICE
                     + (size_t)b * (OH_ * U_) + oo * U_ + u;
    float s = 0.f;
#pragma unroll 16
    for (int i = 0; i < NIH / 2; ++i)
        s += p[(size_t)i * SLICE];
    if (ph) sh[tl] = s;
    __syncthreads();
    if (ph == 0) {
        s += sh[tl];
        float ss = s * s;
        ss += __shfl_xor(ss, 1);
        ss += __shfl_xor(ss, 2);
        ss += __shfl_xor(ss, 4);
        ss += __shfl_xor(ss, 8);
        ss += __shfl_xor(ss, 16);
        float n = sqrtf(ss);
        out[e] = s * n / (1.0f + ss);
    }
}

// ---------------- fallback (atomic path) if ws too small ----------------
#define FTI 4
__global__ __launch_bounds__(256, 2) void caps_main_atomic(const float* __restrict__ x,
                                                           const float* __restrict__ w,
                                                           float* __restrict__ out) {
    __shared__ float xs[FTI * C_ * 33];
    const int tid = threadIdx.x;
    const int i0 = blockIdx.x * FTI;
    for (int k = tid; k < B_ * FTI * C_; k += 256) {
        int b = k >> 6, rem = k & 63;
        xs[rem * 33 + b] = x[(size_t)b * (I_ * C_) + (size_t)i0 * C_ + rem];
    }
    __syncthreads();
    const int o = tid >> 3, u4 = (tid & 7) << 2;
    const float* wp = w + (size_t)i0 * (O_ * C_ * U_) + o * (C_ * U_) + u4;
    float4 acc[B_];
#pragma unroll
    for (int b = 0; b < B_; ++b) acc[b] = make_float4(0.f, 0.f, 0.f, 0.f);
    for (int il = 0; il < FTI; ++il) {
        const float* wpi = wp + (size_t)il * (O_ * C_ * U_);
        const float* xr = &xs[il * C_ * 33];
#pragma unroll
        for (int c = 0; c < C_; ++c) {
            float4 wv = *(const float4*)(wpi + c * U_);
            const float* xc = xr + c * 33;
#pragma unroll
            for (int b = 0; b < B_; ++b) {
                float xb = xc[b];
                acc[b].x = fmaf(xb, wv.x, acc[b].x);
                acc[b].y = fmaf(xb, wv.y, acc[b].y);
                acc[b].z = fmaf(xb, wv.z, acc[b].z);
                acc[b].w = fmaf(xb, wv.w, acc[b].w);
            }
        }
    }
    float* op = out + o * U_ + u4;
#pragma unroll
    for (int b = 0; b < B_; ++b) {
        float* p = op + (size_t)b * NCOL;
        atomicAdd(p + 0, acc[b].x);
        atomicAdd(p + 1, acc[b].y);
        atomicAdd(p + 2, acc[b].z);
        atomicAdd(p + 3, acc[b].w);
    }
}

__global__ void caps_squash_inplace(float* __restrict__ out) {
    int t = blockIdx.x * 256 + threadIdx.x;
    float s = out[t];
    float ss = s * s;
    ss += __shfl_xor(ss, 1);
    ss += __shfl_xor(ss, 2);
    ss += __shfl_xor(ss, 4);
    ss += __shfl_xor(ss, 8);
    ss += __shfl_xor(ss, 16);
    float n = sqrtf(ss);
    out[t] = s * n / (1.0f + ss);
}

extern "C" void kernel_launch(void* const* d_in, const int* in_sizes, int n_in,
                              void* d_out, int out_size, void* d_ws, size_t ws_size,
                              hipStream_t stream) {
    const float* x = (const float*)d_in[0];   // [B, I, C]
    const float* w = (const float*)d_in[1];   // [I, O, C, U]
    float* out = (float*)d_out;               // [B, O, 1, U] = 32768 floats

    const size_t need = (size_t)NBLK * SLICE * sizeof(float);   // 32 MB
    if (ws_size >= need) {
        float* ws = (float*)d_ws;
        caps_partial<<<NBLK, 512, 0, stream>>>(x, w, ws);
        caps_reduce_squash<<<(B_ * NCOL) / 128, 256, 0, stream>>>(ws, out);
    } else {
        hipMemsetAsync(out, 0, (size_t)(B_ * NCOL) * sizeof(float), stream);
        caps_main_atomic<<<I_ / FTI, 256, 0, stream>>>(x, w, out);
        caps_squash_inplace<<<(B_ * NCOL) / 256, 256, 0, stream>>>(out);
    }
}